// Round 10
// baseline (282.116 us; speedup 1.0000x reference)
//
#include <hip/hip_runtime.h>
#include <hip/hip_bf16.h>

// x:[1024,3,32,32] -> conv1(3->64)+relu -> conv2(64->128)+relu -> meanpool
// -> fc(128->256)+b -> *mask -> sage1(256->256)+relu -> sage2(256->128)
// Output [32,32,128] fp32.
//
// Conv structural floor (R1-R8): with <=128 AGPR/wave the operand identity
// (1/nO + 1/(nI*nR)) >= 0.75 b128/MFMA pins LDS+L1 operand time at ~1.3x
// MFMA time; measured wall ~155-157us across 5 structurally different
// schedules. R7 config = champion, kept verbatim.
// R10: tail (prep+fc+sage1+sage2, ~105us for ~1GFLOP/5MB) collapsed into ONE
// kernel per batch row: fc+sage1+sage2 in LDS, no z1/z2 global round-trips,
// 2 fewer launches. 32 blocks x 1024 thr (4 waves/SIMD on 32 CUs).
//
// Workspace layout (<6MB):
//  [0,2M)        pooled4 [1024][4][128] f32 (band partials, pre-divide)
//  [4096K,+256K) l1T  [256][256] = s1lw^T
//  [4352K,+256K) w1pT [256][256] = (s1rw - s1lw/31)^T
//  [4608K,+128K) l2T  [256][128] = s2lw^T
//  [4736K,+128K) w2pT [256][128] = (s2rw - s2lw/31)^T
//  [4864K,+128K) fwT  [128][256] = fc_w^T
//  [4992K,+144K) w2c  [9][4][2][128][8] bf16 conv2 w: [tap][ks][hi][oc][j],
//                ic = ks*16 + hi*8 + j  (B-frag order for 32x32x16 MFMA)
//  [5136K,+4K)   w1b  [64][32] bf16 conv1 w+bias (k=27 slot = bias)

typedef __attribute__((ext_vector_type(8))) short bfrag;
typedef __attribute__((ext_vector_type(4))) float f32x4;
typedef __attribute__((ext_vector_type(16))) float f32x16;

static __device__ __forceinline__ unsigned short f2bf(float f) {
    union { float f; unsigned u; } v; v.f = f;
    unsigned r = v.u + 0x7fff + ((v.u >> 16) & 1);   // RNE (finite)
    return (unsigned short)(r >> 16);
}

// pack two f32 -> two bf16 (RNE) in one instr
static __device__ __forceinline__ unsigned cvtpk(float lo, float hi) {
    unsigned r;
    asm("v_cvt_pk_bf16_f32 %0, %1, %2" : "=v"(r) : "v"(lo), "v"(hi));
    return r;
}

// async global->LDS, 16B per lane (linear dest = wave-uniform base + lane*16)
static __device__ __forceinline__ void gl_lds16(const short* g, short* l) {
    __builtin_amdgcn_global_load_lds(
        (const __attribute__((address_space(1))) unsigned int*)g,
        (__attribute__((address_space(3))) unsigned int*)l, 16, 0, 0);
}

// prep (R8): reads COALESCED (iterate source contiguously; transposed writes
// are fire-and-forget). Strided reads stall the wave, strided writes don't.
__global__ __launch_bounds__(256) void prep_kernel(
    const float* __restrict__ s1lw, const float* __restrict__ s1rw,
    const float* __restrict__ s2lw, const float* __restrict__ s2rw,
    const float* __restrict__ c2w, const float* __restrict__ c1w,
    const float* __restrict__ c1b, const float* __restrict__ fcw,
    float* __restrict__ l1T, float* __restrict__ w1pT,
    float* __restrict__ l2T, float* __restrict__ w2pT,
    float* __restrict__ fwT,
    short* __restrict__ w2c, short* __restrict__ w1b) {
    int i = blockIdx.x * 256 + threadIdx.x;     // grid 288 -> [0, 73728)
    const float inv31 = 1.f / 31.f;
    if (i < 65536) {                            // s1lw/s1rw [256][256]
        int o = i >> 8, d = i & 255;
        float lw = s1lw[i];                     // coalesced
        float rw = s1rw[i];
        l1T[d * 256 + o]  = lw;
        w1pT[d * 256 + o] = rw - lw * inv31;
    }
    if (i < 32768) {
        int o = i >> 8, d = i & 255;            // s2lw/s2rw [128][256]
        float lw = s2lw[i];
        float rw = s2rw[i];
        l2T[d * 128 + o]  = lw;
        w2pT[d * 128 + o] = rw - lw * inv31;
        int o2 = i >> 7, c = i & 127;           // fcw [256][128]
        fwT[c * 256 + o2] = fcw[i];
    }
    if (i < 73728) {                            // c2w [128][64][9] contiguous
        int oc = i / 576, rem = i - oc * 576;
        int ic = rem / 9, tap = rem - ic * 9;
        int widx = tap * 8192 + (ic >> 4) * 2048 + ((ic >> 3) & 1) * 1024
                 + oc * 8 + (ic & 7);
        w2c[widx] = (short)f2bf(c2w[i]);
    }
    if (i < 2048) {                             // w1b[oc][k], k=27 -> bias
        int oc = i >> 5, k = i & 31;
        float v = (k < 27) ? c1w[oc * 27 + k] : (k == 27 ? c1b[oc] : 0.f);
        w1b[i] = (short)f2bf(v);
    }
}

// Fused conv1+conv2+pool: grid (4 bands of 8 rows, 1024 imgs). = R7 champion.
__global__ __launch_bounds__(256, 2) void fused_conv_kernel(
    const float* __restrict__ x, const short* __restrict__ w1b,
    const short* __restrict__ w2c, const float* __restrict__ b2,
    float* __restrict__ pooled4) {
    const int band = blockIdx.x, img = blockIdx.y;
    __shared__ short xt[3 * 12 * 34];     // 2448 B: input rows band*8-2..band*8+9
    __shared__ short c1t[10 * 34 * 72];   // 48960 B [row][col pad34][ic pad72]
    __shared__ short bufB[3][4096];       // 24576 B: 3 x 8KB K-step chunks of w2c
    __shared__ float wsum[4][128];
    const int t = threadIdx.x;
    const int w = t >> 6, lane = t & 63;
    const int ln15 = lane & 15, q8 = (lane >> 4) * 8;
    const int ln31 = lane & 31, hi = lane >> 5;

    // stage xt (zero-padded), zero c1t pad cols 0/33
    const float* xi = x + img * 3072;
    for (int idx = t; idx < 1224; idx += 256) {
        int c = idx / 408, rem = idx % 408, r = rem / 34, col = rem % 34;
        int y = band * 8 - 2 + r, xx = col - 1;
        float v = 0.f;
        if ((unsigned)y < 32u && (unsigned)xx < 32u) v = xi[c * 1024 + y * 32 + xx];
        xt[idx] = (short)f2bf(v);
    }
    {
        f32x4 z = {0.f, 0.f, 0.f, 0.f};
        for (int i = t; i < 180; i += 256) {          // 10r x 2c x 9 f32x4
            int r = i / 18, rem = i % 18, side = rem / 9, q = rem % 9;
            *(f32x4*)(c1t + (r * 34 + side * 33) * 72 + q * 8) = z;
        }
    }
    bfrag b1f[4];
#pragma unroll
    for (int ot = 0; ot < 4; ++ot)
        b1f[ot] = *(const bfrag*)(w1b + (ot * 16 + ln15) * 32 + q8);

    // hoisted per-lane conv1 tap decomposition (invariant over pos tiles)
    int xOff[8]; int kMask[8]; int kOvr[8];
#pragma unroll
    for (int j = 0; j < 8; ++j) {
        int k = q8 + j;
        int c = (k * 57) >> 9;               // k/9 for k<36
        int rem = k - 9 * c;
        int dy = (rem * 11) >> 5;            // rem/3 for rem<9
        int dx = rem - 3 * dy;
        int cc = c < 3 ? c : 2;              // clamp for safe read
        xOff[j] = cc * 408 + dy * 34 + dx;
        kMask[j] = (c < 3) ? 0xFFFF : 0;
        kOvr[j]  = (c < 3) ? 0 : (k == 27 ? 0x3F80 : 0);
    }
    __syncthreads();

    // issue B stage for steps 0,1 now; latency hides under phase A; the
    // phase A->B __syncthreads (full vmcnt drain) is the completion point.
    {
        const short* src = w2c + t * 8;
        short* dst = (short*)bufB + t * 8;
        gl_lds16(src, dst);                   // st0 lo half
        gl_lds16(src + 2048, dst + 2048);     // st0 hi half
        gl_lds16(src + 4096, dst + 4096);     // st1 lo half
        gl_lds16(src + 6144, dst + 6144);     // st1 hi half
    }

    // ---- phase A: conv1 -> c1t. 20 pos-tiles of 16 (10 rows x 32 cols);
    //      wave w -> tiles 5w..5w+4. weights = A-operand, x patch = B. ----
#pragma unroll 1
    for (int pt = 0; pt < 5; ++pt) {
        const int tile = w * 5 + pt;
        const int r = tile >> 1, xcb = (tile & 1) << 4;
        const int baseA = r * 34 + xcb + ln15;
        bfrag a1f;                            // x patch (B-operand)
#pragma unroll
        for (int j = 0; j < 8; ++j)
            a1f[j] = (short)((xt[xOff[j] + baseA] & kMask[j]) | kOvr[j]);
        f32x4 acc1[4];
#pragma unroll
        for (int ot = 0; ot < 4; ++ot) {
#pragma unroll
            for (int rg = 0; rg < 4; ++rg) acc1[ot][rg] = 0.f;
            acc1[ot] = __builtin_amdgcn_mfma_f32_16x16x32_bf16(
                b1f[ot], a1f, acc1[ot], 0, 0, 0);
        }
        // D: row = oc (ot*16 + (lane>>4)*4 + rg), col = pos (tile*16 + ln15).
        const int y = band * 8 - 1 + r;
        const bool valid = (unsigned)y < 32u;    // wave-uniform
        const int waddr = (r * 34 + xcb + ln15 + 1) * 72 + (lane >> 4) * 4;
#pragma unroll
        for (int ot = 0; ot < 4; ++ot) {
            uint2 pk = {0u, 0u};
            if (valid) {
                pk.x = cvtpk(fmaxf(acc1[ot][0], 0.f), fmaxf(acc1[ot][1], 0.f));
                pk.y = cvtpk(fmaxf(acc1[ot][2], 0.f), fmaxf(acc1[ot][3], 0.f));
            }
            *(uint2*)&c1t[waddr + ot * 16] = pk;
        }
    }
    __syncthreads();   // c1t ready + bufB st0/st1 staged (full vmcnt drain)

    // ---- phase B: conv2, 32x32x16 MFMA. wave = 2 rows x 32 cols x 128 oc ----
    float b2v[4];
#pragma unroll
    for (int ot = 0; ot < 4; ++ot) b2v[ot] = b2[ot * 32 + ln31];

    f32x16 acc[2][4];
#pragma unroll
    for (int pt = 0; pt < 2; ++pt)
#pragma unroll
        for (int ot = 0; ot < 4; ++ot)
#pragma unroll
            for (int rg = 0; rg < 16; ++rg) acc[pt][ot][rg] = 0.f;

    // A-frag 32x32x16: row = lane&31 (image col), k = (lane>>5)*8 + j (ic)
    const int aB0 = (w * 2 * 34 + ln31) * 72 + hi * 8;
    const int aB1 = aB0 + 34 * 72;
    const int bOff = hi * 1024 + ln31 * 8;    // within an 8KB step chunk
    const short* stSrc = w2c + t * 8;         // staging source base
    short* stDst = (short*)bufB + t * 8;      // staging dest base

    auto stage = [&](int st) {                // 8KB step chunk -> buf st%3
        const short* src = stSrc + st * 4096;
        short* dst = stDst + (st % 3) * 4096;
        gl_lds16(src, dst);
        gl_lds16(src + 2048, dst + 2048);
    };
    auto prefB = [&](bfrag* bf, int st) {     // B-frags for step st from LDS
        const short* bc = (const short*)bufB + (st % 3) * 4096 + bOff;
#pragma unroll
        for (int kk = 0; kk < 2; ++kk)
#pragma unroll
            for (int ot = 0; ot < 4; ++ot)
                bf[kk * 4 + ot] = *(const bfrag*)(bc + kk * 2048 + ot * 256);
    };
    auto body = [&](int st, const bfrag* bCur, bfrag* bNext) {
        if (st + 2 < 18) stage(st + 2);
        const int tap = st >> 1, kh = st & 1;
        const int dy = (tap * 11) >> 5, dx = tap - 3 * dy;
        const int aOff = (dy * 34 + dx) * 72 + kh * 32;
        bfrag af0 = *(const bfrag*)&c1t[aB0 + aOff];   // af first: first MFMA
        bfrag af1 = *(const bfrag*)&c1t[aB0 + aOff + 16];  // waits only af0
        bfrag af2 = *(const bfrag*)&c1t[aB1 + aOff];
        bfrag af3 = *(const bfrag*)&c1t[aB1 + aOff + 16];
        if (st + 1 < 18) prefB(bNext, st + 1);   // completes under MFMAs
        __builtin_amdgcn_s_setprio(1);
#pragma unroll
        for (int ot = 0; ot < 4; ++ot)
            acc[0][ot] = __builtin_amdgcn_mfma_f32_32x32x16_bf16(
                af0, bCur[ot], acc[0][ot], 0, 0, 0);
#pragma unroll
        for (int ot = 0; ot < 4; ++ot)
            acc[0][ot] = __builtin_amdgcn_mfma_f32_32x32x16_bf16(
                af1, bCur[4 + ot], acc[0][ot], 0, 0, 0);
#pragma unroll
        for (int ot = 0; ot < 4; ++ot)
            acc[1][ot] = __builtin_amdgcn_mfma_f32_32x32x16_bf16(
                af2, bCur[ot], acc[1][ot], 0, 0, 0);
#pragma unroll
        for (int ot = 0; ot < 4; ++ot)
            acc[1][ot] = __builtin_amdgcn_mfma_f32_32x32x16_bf16(
                af3, bCur[4 + ot], acc[1][ot], 0, 0, 0);
        __builtin_amdgcn_s_setprio(0);
        // drain own stage(st+2) (issued ~600cyc ago) so after the barrier all
        // waves may read buf[(st+2)%3]'s predecessor-free data next body.
        asm volatile("s_waitcnt vmcnt(0)" ::: "memory");
        __builtin_amdgcn_s_barrier();
    };

    bfrag bX[8], bY[8];
    prefB(bX, 0);                             // buf0/buf1 complete (syncthreads)
#pragma unroll 1
    for (int st = 0; st < 18; st += 2) {      // X/Y shadow-reg pipeline
        body(st, bX, bY);
        body(st + 1, bY, bX);
    }

    // bias + relu + pool. 32x32 C/D: col(lane&31)=oc, rows spread over
    // regs & half-wave -> per-lane partial covers 16 of 32 rows; xor 32.
#pragma unroll
    for (int ot = 0; ot < 4; ++ot) {
        float s = 0.f;
#pragma unroll
        for (int pt = 0; pt < 2; ++pt)
#pragma unroll
            for (int rg = 0; rg < 16; ++rg)
                s += fmaxf(acc[pt][ot][rg] + b2v[ot], 0.f);
        s += __shfl_xor(s, 32, 64);
        if (lane < 32) wsum[w][ot * 32 + ln31] = s;
    }
    __syncthreads();
    if (t < 128) {
        pooled4[((size_t)img * 4 + band) * 128 + t] =
            wsum[0][t] + wsum[1][t] + wsum[2][t] + wsum[3][t];
    }
}

// sage_fused (R10): grid 32 (one block per batch row bb), 1024 threads.
// fc + sage1 + sage2 entirely in LDS: m[32][128] -> h=z1[32][256] ->
// z2[32][256] -> out. Weights streamed from L2 (shared by all 32 blocks).
// All fp32, same accumulation granularity as the split kernels.
__global__ __launch_bounds__(1024) void sage_fused_kernel(
    const float* __restrict__ pooled4, const float* __restrict__ fwT,
    const float* __restrict__ fb, const float* __restrict__ mask,
    const float* __restrict__ l1T, const float* __restrict__ lb1,
    const float* __restrict__ w1pT,
    const float* __restrict__ l2T, const float* __restrict__ lb2,
    const float* __restrict__ w2pT, float* __restrict__ out) {
    const int bb = blockIdx.x;
    __shared__ float m[32 * 128];      // 16KB pooled means
    __shared__ float h[32 * 256];      // 32KB z1
    __shared__ float z2l[32 * 256];    // 32KB z2
    __shared__ float sl[256];
    __shared__ float cf[256];          // c1 final / (low 128) c2 final
    __shared__ float sc4[4][256];      // 4KB scratch (node-sum / c1 partials)
    __shared__ float sc8[8][128];      // 4KB scratch (c2 partials)
    const int t = threadIdx.x;

    // ---- pooled means: m[i][c] = sum of 4 band partials / 1024 ----
    for (int idx = t; idx < 4096; idx += 1024) {
        int i = idx >> 7, c = idx & 127;
        const float* p = pooled4 + ((size_t)(bb * 32 + i) * 4) * 128 + c;
        m[idx] = (p[0] + p[128] + p[256] + p[384]) * (1.f / 1024.f);
    }
    __syncthreads();

    // ---- fc: h[i][o] = (m[i]·fwT[:,o] + fb[o]) * mask. thread = (o, ig) ----
    {
        const int o = t & 255, ig = t >> 8;           // ig: 4 groups of 8 imgs
        float acc[8];
#pragma unroll
        for (int i = 0; i < 8; ++i) acc[i] = 0.f;
        for (int c0 = 0; c0 < 128; c0 += 4) {
            float wv0 = fwT[(c0 + 0) * 256 + o];
            float wv1 = fwT[(c0 + 1) * 256 + o];
            float wv2 = fwT[(c0 + 2) * 256 + o];
            float wv3 = fwT[(c0 + 3) * 256 + o];
#pragma unroll
            for (int i = 0; i < 8; ++i) {
                f32x4 hv = *(const f32x4*)&m[(ig * 8 + i) * 128 + c0];
                acc[i] = fmaf(hv[0], wv0, acc[i]);
                acc[i] = fmaf(hv[1], wv1, acc[i]);
                acc[i] = fmaf(hv[2], wv2, acc[i]);
                acc[i] = fmaf(hv[3], wv3, acc[i]);
            }
        }
        const float b = fb[o];
#pragma unroll
        for (int i = 0; i < 8; ++i) {
            const int n = ig * 8 + i;
            h[n * 256 + o] = (acc[i] + b) * mask[bb * 32 + n];
        }
    }
    __syncthreads();

    // ---- sage1 node-sum -> sl ----
    {
        const int col = t & 255, q = t >> 8;
        float s = 0.f;
#pragma unroll
        for (int n = 0; n < 8; ++n) s += h[(q * 8 + n) * 256 + col];
        sc4[q][col] = s;
    }
    __syncthreads();
    if (t < 256) sl[t] = (sc4[0][t] + sc4[1][t] + sc4[2][t] + sc4[3][t]) * (1.f / 31.f);
    __syncthreads();

    // ---- c1[o] = sl·l1T[:,o] (d-quarters) ----
    {
        const int o = t & 255, dq = t >> 8;
        float c = 0.f;
#pragma unroll 4
        for (int d = 0; d < 64; ++d)
            c = fmaf(sl[dq * 64 + d], l1T[(dq * 64 + d) * 256 + o], c);
        sc4[dq][o] = c;
    }
    __syncthreads();
    if (t < 256) cf[t] = sc4[0][t] + sc4[1][t] + sc4[2][t] + sc4[3][t] + lb1[t];
    __syncthreads();

    // ---- sage1 per-node: z2[n][o] = relu(h[n]·w1pT[:,o] + c1[o]) ----
    {
        const int o = t & 255, ng = t >> 8;           // 4 groups of 8 nodes
        float acc[8];
#pragma unroll
        for (int i = 0; i < 8; ++i) acc[i] = 0.f;
        for (int d0 = 0; d0 < 256; d0 += 4) {
            float wv0 = w1pT[(d0 + 0) * 256 + o];
            float wv1 = w1pT[(d0 + 1) * 256 + o];
            float wv2 = w1pT[(d0 + 2) * 256 + o];
            float wv3 = w1pT[(d0 + 3) * 256 + o];
#pragma unroll
            for (int i = 0; i < 8; ++i) {
                f32x4 hv = *(const f32x4*)&h[(ng * 8 + i) * 256 + d0];
                acc[i] = fmaf(hv[0], wv0, acc[i]);
                acc[i] = fmaf(hv[1], wv1, acc[i]);
                acc[i] = fmaf(hv[2], wv2, acc[i]);
                acc[i] = fmaf(hv[3], wv3, acc[i]);
            }
        }
        const float c1 = cf[o];
#pragma unroll
        for (int i = 0; i < 8; ++i)
            z2l[(ng * 8 + i) * 256 + o] = fmaxf(acc[i] + c1, 0.f);
    }
    __syncthreads();

    // ---- sage2 node-sum -> sl (reuse) ----
    {
        const int col = t & 255, q = t >> 8;
        float s = 0.f;
#pragma unroll
        for (int n = 0; n < 8; ++n) s += z2l[(q * 8 + n) * 256 + col];
        sc4[q][col] = s;
    }
    __syncthreads();
    if (t < 256) sl[t] = (sc4[0][t] + sc4[1][t] + sc4[2][t] + sc4[3][t]) * (1.f / 31.f);
    __syncthreads();

    // ---- c2[o] = sl·l2T[:,o] (d-eighths, 128 outs) ----
    {
        const int o = t & 127, dg = t >> 7;
        float c = 0.f;
#pragma unroll 4
        for (int d = 0; d < 32; ++d)
            c = fmaf(sl[dg * 32 + d], l2T[(dg * 32 + d) * 128 + o], c);
        sc8[dg][o] = c;
    }
    __syncthreads();
    if (t < 128) {
        cf[t] = sc8[0][t] + sc8[1][t] + sc8[2][t] + sc8[3][t] +
                sc8[4][t] + sc8[5][t] + sc8[6][t] + sc8[7][t] + lb2[t];
    }
    __syncthreads();

    // ---- sage2 per-node: out[n][o] = z2[n]·w2pT[:,o] + c2[o] ----
    {
        const int o = t & 127, ng = t >> 7;           // 8 groups of 4 nodes
        float acc[4];
#pragma unroll
        for (int i = 0; i < 4; ++i) acc[i] = 0.f;
        for (int d0 = 0; d0 < 256; d0 += 4) {
            float wv0 = w2pT[(d0 + 0) * 128 + o];
            float wv1 = w2pT[(d0 + 1) * 128 + o];
            float wv2 = w2pT[(d0 + 2) * 128 + o];
            float wv3 = w2pT[(d0 + 3) * 128 + o];
#pragma unroll
            for (int i = 0; i < 4; ++i) {
                f32x4 hv = *(const f32x4*)&z2l[(ng * 4 + i) * 256 + d0];
                acc[i] = fmaf(hv[0], wv0, acc[i]);
                acc[i] = fmaf(hv[1], wv1, acc[i]);
                acc[i] = fmaf(hv[2], wv2, acc[i]);
                acc[i] = fmaf(hv[3], wv3, acc[i]);
            }
        }
        const float c2 = cf[o];
#pragma unroll
        for (int i = 0; i < 4; ++i)
            out[(size_t)(bb * 32 + ng * 4 + i) * 128 + o] = acc[i] + c2;
    }
}

extern "C" void kernel_launch(void* const* d_in, const int* in_sizes, int n_in,
                              void* d_out, int out_size, void* d_ws, size_t ws_size,
                              hipStream_t stream) {
    const float* x    = (const float*)d_in[0];
    const float* mask = (const float*)d_in[1];
    const float* c1w  = (const float*)d_in[2];
    const float* c1b  = (const float*)d_in[3];
    const float* c2w  = (const float*)d_in[4];
    const float* c2b  = (const float*)d_in[5];
    const float* fcw  = (const float*)d_in[6];
    const float* fcb  = (const float*)d_in[7];
    const float* s1lw = (const float*)d_in[8];
    const float* s1lb = (const float*)d_in[9];
    const float* s1rw = (const float*)d_in[10];
    const float* s2lw = (const float*)d_in[11];
    const float* s2lb = (const float*)d_in[12];
    const float* s2rw = (const float*)d_in[13];
    float* out = (float*)d_out;

    char* ws = (char*)d_ws;
    float* pooled4 = (float*)(ws);
    float* l1T     = (float*)(ws + 4096u * 1024);
    float* w1pT    = (float*)(ws + 4352u * 1024);
    float* l2T     = (float*)(ws + 4608u * 1024);
    float* w2pT    = (float*)(ws + 4736u * 1024);
    float* fwT     = (float*)(ws + 4864u * 1024);
    short* w2c     = (short*)(ws + 4992u * 1024);
    short* w1b     = (short*)(ws + 5136u * 1024);

    prep_kernel<<<dim3(288), 256, 0, stream>>>(s1lw, s1rw, s2lw, s2rw, c2w, c1w, c1b,
                                               fcw, l1T, w1pT, l2T, w2pT, fwT, w2c, w1b);
    fused_conv_kernel<<<dim3(4, 1024), 256, 0, stream>>>(x, w1b, w2c, c2b, pooled4);
    sage_fused_kernel<<<dim3(32), 1024, 0, stream>>>(pooled4, fwT, fcb, mask,
                                                     l1T, s1lb, w1pT,
                                                     l2T, s2lb, w2pT, out);
}

// Round 11
// 260.621 us; speedup vs baseline: 1.0825x; 1.0825x over previous
//
#include <hip/hip_runtime.h>
#include <hip/hip_bf16.h>

// x:[1024,3,32,32] -> conv1(3->64)+relu -> conv2(64->128)+relu -> meanpool
// -> fc(128->256)+b -> *mask -> sage1(256->256)+relu -> sage2(256->128)
// Output [32,32,128] fp32.
//
// == R11: measured-champion restore (R9 config, 260.9us) ==
// Conv structural floor (R1-R8): with <=128 AGPR/wave the operand identity
// (1/nP + 1/nO) >= 0.71 b128/MFMA pins operand-pipe time ~= MFMA time, and
// per-CU pipe times empirically SUM on this structure (8 variants, all
// >=155us: 2/4 waves-SIMD, barriers/none, B via L1/LDS/split; 256-AGPR
// spills (R5), fp8 rejected on absmax headroom). Tail: split beats fused
// (R10 regression); d-split sages beat 256-block (R7); fc variants neutral.
//
// Workspace layout (<6MB):
//  [0,2M)        pooled4 [1024][4][128] f32 (band partials, pre-divide)
//  [2M,3M)       z1 [1024][256]
//  [3M,4M)       z2 [1024][256]
//  [4096K,+256K) l1T  [256][256] = s1lw^T
//  [4352K,+256K) w1pT [256][256] = (s1rw - s1lw/31)^T
//  [4608K,+128K) l2T  [256][128] = s2lw^T
//  [4736K,+128K) w2pT [256][128] = (s2rw - s2lw/31)^T
//  [4864K,+128K) fwT  [128][256] = fc_w^T
//  [4992K,+144K) w2c  [9][4][2][128][8] bf16 conv2 w: [tap][ks][hi][oc][j],
//                ic = ks*16 + hi*8 + j  (B-frag order for 32x32x16 MFMA)
//  [5136K,+4K)   w1b  [64][32] bf16 conv1 w+bias (k=27 slot = bias)

typedef __attribute__((ext_vector_type(8))) short bfrag;
typedef __attribute__((ext_vector_type(4))) float f32x4;
typedef __attribute__((ext_vector_type(16))) float f32x16;

static __device__ __forceinline__ unsigned short f2bf(float f) {
    union { float f; unsigned u; } v; v.f = f;
    unsigned r = v.u + 0x7fff + ((v.u >> 16) & 1);   // RNE (finite)
    return (unsigned short)(r >> 16);
}

// pack two f32 -> two bf16 (RNE) in one instr
static __device__ __forceinline__ unsigned cvtpk(float lo, float hi) {
    unsigned r;
    asm("v_cvt_pk_bf16_f32 %0, %1, %2" : "=v"(r) : "v"(lo), "v"(hi));
    return r;
}

// async global->LDS, 16B per lane (linear dest = wave-uniform base + lane*16)
static __device__ __forceinline__ void gl_lds16(const short* g, short* l) {
    __builtin_amdgcn_global_load_lds(
        (const __attribute__((address_space(1))) unsigned int*)g,
        (__attribute__((address_space(3))) unsigned int*)l, 16, 0, 0);
}

// prep (R8): reads COALESCED (iterate source contiguously; transposed writes
// are fire-and-forget). Strided reads stall the wave, strided writes don't.
__global__ __launch_bounds__(256) void prep_kernel(
    const float* __restrict__ s1lw, const float* __restrict__ s1rw,
    const float* __restrict__ s2lw, const float* __restrict__ s2rw,
    const float* __restrict__ c2w, const float* __restrict__ c1w,
    const float* __restrict__ c1b, const float* __restrict__ fcw,
    float* __restrict__ l1T, float* __restrict__ w1pT,
    float* __restrict__ l2T, float* __restrict__ w2pT,
    float* __restrict__ fwT,
    short* __restrict__ w2c, short* __restrict__ w1b) {
    int i = blockIdx.x * 256 + threadIdx.x;     // grid 288 -> [0, 73728)
    const float inv31 = 1.f / 31.f;
    if (i < 65536) {                            // s1lw/s1rw [256][256]
        int o = i >> 8, d = i & 255;
        float lw = s1lw[i];                     // coalesced
        float rw = s1rw[i];
        l1T[d * 256 + o]  = lw;
        w1pT[d * 256 + o] = rw - lw * inv31;
    }
    if (i < 32768) {
        int o = i >> 8, d = i & 255;            // s2lw/s2rw [128][256]
        float lw = s2lw[i];
        float rw = s2rw[i];
        l2T[d * 128 + o]  = lw;
        w2pT[d * 128 + o] = rw - lw * inv31;
        int o2 = i >> 7, c = i & 127;           // fcw [256][128]
        fwT[c * 256 + o2] = fcw[i];
    }
    if (i < 73728) {                            // c2w [128][64][9] contiguous
        int oc = i / 576, rem = i - oc * 576;
        int ic = rem / 9, tap = rem - ic * 9;
        int widx = tap * 8192 + (ic >> 4) * 2048 + ((ic >> 3) & 1) * 1024
                 + oc * 8 + (ic & 7);
        w2c[widx] = (short)f2bf(c2w[i]);
    }
    if (i < 2048) {                             // w1b[oc][k], k=27 -> bias
        int oc = i >> 5, k = i & 31;
        float v = (k < 27) ? c1w[oc * 27 + k] : (k == 27 ? c1b[oc] : 0.f);
        w1b[i] = (short)f2bf(v);
    }
}

// Fused conv1+conv2+pool: grid (4 bands of 8 rows, 1024 imgs). = R7 champion.
__global__ __launch_bounds__(256, 2) void fused_conv_kernel(
    const float* __restrict__ x, const short* __restrict__ w1b,
    const short* __restrict__ w2c, const float* __restrict__ b2,
    float* __restrict__ pooled4) {
    const int band = blockIdx.x, img = blockIdx.y;
    __shared__ short xt[3 * 12 * 34];     // 2448 B: input rows band*8-2..band*8+9
    __shared__ short c1t[10 * 34 * 72];   // 48960 B [row][col pad34][ic pad72]
    __shared__ short bufB[3][4096];       // 24576 B: 3 x 8KB K-step chunks of w2c
    __shared__ float wsum[4][128];
    const int t = threadIdx.x;
    const int w = t >> 6, lane = t & 63;
    const int ln15 = lane & 15, q8 = (lane >> 4) * 8;
    const int ln31 = lane & 31, hi = lane >> 5;

    // stage xt (zero-padded), zero c1t pad cols 0/33
    const float* xi = x + img * 3072;
    for (int idx = t; idx < 1224; idx += 256) {
        int c = idx / 408, rem = idx % 408, r = rem / 34, col = rem % 34;
        int y = band * 8 - 2 + r, xx = col - 1;
        float v = 0.f;
        if ((unsigned)y < 32u && (unsigned)xx < 32u) v = xi[c * 1024 + y * 32 + xx];
        xt[idx] = (short)f2bf(v);
    }
    {
        f32x4 z = {0.f, 0.f, 0.f, 0.f};
        for (int i = t; i < 180; i += 256) {          // 10r x 2c x 9 f32x4
            int r = i / 18, rem = i % 18, side = rem / 9, q = rem % 9;
            *(f32x4*)(c1t + (r * 34 + side * 33) * 72 + q * 8) = z;
        }
    }
    bfrag b1f[4];
#pragma unroll
    for (int ot = 0; ot < 4; ++ot)
        b1f[ot] = *(const bfrag*)(w1b + (ot * 16 + ln15) * 32 + q8);

    // hoisted per-lane conv1 tap decomposition (invariant over pos tiles)
    int xOff[8]; int kMask[8]; int kOvr[8];
#pragma unroll
    for (int j = 0; j < 8; ++j) {
        int k = q8 + j;
        int c = (k * 57) >> 9;               // k/9 for k<36
        int rem = k - 9 * c;
        int dy = (rem * 11) >> 5;            // rem/3 for rem<9
        int dx = rem - 3 * dy;
        int cc = c < 3 ? c : 2;              // clamp for safe read
        xOff[j] = cc * 408 + dy * 34 + dx;
        kMask[j] = (c < 3) ? 0xFFFF : 0;
        kOvr[j]  = (c < 3) ? 0 : (k == 27 ? 0x3F80 : 0);
    }
    __syncthreads();

    // issue B stage for steps 0,1 now; latency hides under phase A; the
    // phase A->B __syncthreads (full vmcnt drain) is the completion point.
    {
        const short* src = w2c + t * 8;
        short* dst = (short*)bufB + t * 8;
        gl_lds16(src, dst);                   // st0 lo half
        gl_lds16(src + 2048, dst + 2048);     // st0 hi half
        gl_lds16(src + 4096, dst + 4096);     // st1 lo half
        gl_lds16(src + 6144, dst + 6144);     // st1 hi half
    }

    // ---- phase A: conv1 -> c1t. 20 pos-tiles of 16 (10 rows x 32 cols);
    //      wave w -> tiles 5w..5w+4. weights = A-operand, x patch = B. ----
#pragma unroll 1
    for (int pt = 0; pt < 5; ++pt) {
        const int tile = w * 5 + pt;
        const int r = tile >> 1, xcb = (tile & 1) << 4;
        const int baseA = r * 34 + xcb + ln15;
        bfrag a1f;                            // x patch (B-operand)
#pragma unroll
        for (int j = 0; j < 8; ++j)
            a1f[j] = (short)((xt[xOff[j] + baseA] & kMask[j]) | kOvr[j]);
        f32x4 acc1[4];
#pragma unroll
        for (int ot = 0; ot < 4; ++ot) {
#pragma unroll
            for (int rg = 0; rg < 4; ++rg) acc1[ot][rg] = 0.f;
            acc1[ot] = __builtin_amdgcn_mfma_f32_16x16x32_bf16(
                b1f[ot], a1f, acc1[ot], 0, 0, 0);
        }
        // D: row = oc (ot*16 + (lane>>4)*4 + rg), col = pos (tile*16 + ln15).
        const int y = band * 8 - 1 + r;
        const bool valid = (unsigned)y < 32u;    // wave-uniform
        const int waddr = (r * 34 + xcb + ln15 + 1) * 72 + (lane >> 4) * 4;
#pragma unroll
        for (int ot = 0; ot < 4; ++ot) {
            uint2 pk = {0u, 0u};
            if (valid) {
                pk.x = cvtpk(fmaxf(acc1[ot][0], 0.f), fmaxf(acc1[ot][1], 0.f));
                pk.y = cvtpk(fmaxf(acc1[ot][2], 0.f), fmaxf(acc1[ot][3], 0.f));
            }
            *(uint2*)&c1t[waddr + ot * 16] = pk;
        }
    }
    __syncthreads();   // c1t ready + bufB st0/st1 staged (full vmcnt drain)

    // ---- phase B: conv2, 32x32x16 MFMA. wave = 2 rows x 32 cols x 128 oc ----
    float b2v[4];
#pragma unroll
    for (int ot = 0; ot < 4; ++ot) b2v[ot] = b2[ot * 32 + ln31];

    f32x16 acc[2][4];
#pragma unroll
    for (int pt = 0; pt < 2; ++pt)
#pragma unroll
        for (int ot = 0; ot < 4; ++ot)
#pragma unroll
            for (int rg = 0; rg < 16; ++rg) acc[pt][ot][rg] = 0.f;

    // A-frag 32x32x16: row = lane&31 (image col), k = (lane>>5)*8 + j (ic)
    const int aB0 = (w * 2 * 34 + ln31) * 72 + hi * 8;
    const int aB1 = aB0 + 34 * 72;
    const int bOff = hi * 1024 + ln31 * 8;    // within an 8KB step chunk
    const short* stSrc = w2c + t * 8;         // staging source base
    short* stDst = (short*)bufB + t * 8;      // staging dest base

    auto stage = [&](int st) {                // 8KB step chunk -> buf st%3
        const short* src = stSrc + st * 4096;
        short* dst = stDst + (st % 3) * 4096;
        gl_lds16(src, dst);
        gl_lds16(src + 2048, dst + 2048);
    };
    auto prefB = [&](bfrag* bf, int st) {     // B-frags for step st from LDS
        const short* bc = (const short*)bufB + (st % 3) * 4096 + bOff;
#pragma unroll
        for (int kk = 0; kk < 2; ++kk)
#pragma unroll
            for (int ot = 0; ot < 4; ++ot)
                bf[kk * 4 + ot] = *(const bfrag*)(bc + kk * 2048 + ot * 256);
    };
    auto body = [&](int st, const bfrag* bCur, bfrag* bNext) {
        if (st + 2 < 18) stage(st + 2);
        const int tap = st >> 1, kh = st & 1;
        const int dy = (tap * 11) >> 5, dx = tap - 3 * dy;
        const int aOff = (dy * 34 + dx) * 72 + kh * 32;
        bfrag af0 = *(const bfrag*)&c1t[aB0 + aOff];   // af first: first MFMA
        bfrag af1 = *(const bfrag*)&c1t[aB0 + aOff + 16];  // waits only af0
        bfrag af2 = *(const bfrag*)&c1t[aB1 + aOff];
        bfrag af3 = *(const bfrag*)&c1t[aB1 + aOff + 16];
        if (st + 1 < 18) prefB(bNext, st + 1);   // completes under MFMAs
        __builtin_amdgcn_s_setprio(1);
#pragma unroll
        for (int ot = 0; ot < 4; ++ot)
            acc[0][ot] = __builtin_amdgcn_mfma_f32_32x32x16_bf16(
                af0, bCur[ot], acc[0][ot], 0, 0, 0);
#pragma unroll
        for (int ot = 0; ot < 4; ++ot)
            acc[0][ot] = __builtin_amdgcn_mfma_f32_32x32x16_bf16(
                af1, bCur[4 + ot], acc[0][ot], 0, 0, 0);
#pragma unroll
        for (int ot = 0; ot < 4; ++ot)
            acc[1][ot] = __builtin_amdgcn_mfma_f32_32x32x16_bf16(
                af2, bCur[ot], acc[1][ot], 0, 0, 0);
#pragma unroll
        for (int ot = 0; ot < 4; ++ot)
            acc[1][ot] = __builtin_amdgcn_mfma_f32_32x32x16_bf16(
                af3, bCur[4 + ot], acc[1][ot], 0, 0, 0);
        __builtin_amdgcn_s_setprio(0);
        // drain own stage(st+2) (issued ~600cyc ago) so after the barrier all
        // waves may read buf[(st+2)%3]'s predecessor-free data next body.
        asm volatile("s_waitcnt vmcnt(0)" ::: "memory");
        __builtin_amdgcn_s_barrier();
    };

    bfrag bX[8], bY[8];
    prefB(bX, 0);                             // buf0/buf1 complete (syncthreads)
#pragma unroll 1
    for (int st = 0; st < 18; st += 2) {      // X/Y shadow-reg pipeline
        body(st, bX, bY);
        body(st + 1, bY, bX);
    }

    // bias + relu + pool. 32x32 C/D: col(lane&31)=oc, rows spread over
    // regs & half-wave -> per-lane partial covers 16 of 32 rows; xor 32.
#pragma unroll
    for (int ot = 0; ot < 4; ++ot) {
        float s = 0.f;
#pragma unroll
        for (int pt = 0; pt < 2; ++pt)
#pragma unroll
            for (int rg = 0; rg < 16; ++rg)
                s += fmaxf(acc[pt][ot][rg] + b2v[ot], 0.f);
        s += __shfl_xor(s, 32, 64);
        if (lane < 32) wsum[w][ot * 32 + ln31] = s;
    }
    __syncthreads();
    if (t < 128) {
        pooled4[((size_t)img * 4 + band) * 128 + t] =
            wsum[0][t] + wsum[1][t] + wsum[2][t] + wsum[3][t];
    }
}

// fc: grid 256 (4 images per block) -- amortizes fwT L2 refetch 4x.
__global__ __launch_bounds__(256) void fc_kernel(
    const float* __restrict__ pooled4, const float* __restrict__ fwT,
    const float* __restrict__ fb, const float* __restrict__ mask,
    float* __restrict__ z1) {
    const int g = blockIdx.x;
    __shared__ float m[4][128];
    const int t = threadIdx.x;
    if (t < 128) {
#pragma unroll
        for (int i = 0; i < 4; ++i) {
            const float* p = pooled4 + (size_t)(g * 4 + i) * 4 * 128 + t;
            m[i][t] = (p[0] + p[128] + p[256] + p[384]) * (1.f / 1024.f);
        }
    }
    __syncthreads();
    float a0 = fb[t], a1 = a0, a2 = a0, a3 = a0;
#pragma unroll 4
    for (int c = 0; c < 128; ++c) {
        float wv = fwT[c * 256 + t];                 // coalesced
        a0 = fmaf(m[0][c], wv, a0);
        a1 = fmaf(m[1][c], wv, a1);
        a2 = fmaf(m[2][c], wv, a2);
        a3 = fmaf(m[3][c], wv, a3);
    }
    z1[(g * 4 + 0) * 256 + t] = a0 * mask[g * 4 + 0];
    z1[(g * 4 + 1) * 256 + t] = a1 * mask[g * 4 + 1];
    z1[(g * 4 + 2) * 256 + t] = a2 * mask[g * 4 + 2];
    z1[(g * 4 + 3) * 256 + t] = a3 * mask[g * 4 + 3];
}

// sage1+relu: grid 512 = (bb 32, chunk 8, ohalf 2). Block = 4 nodes x 128
// outputs x 2 d-halves (256 thr). d-split halves the serial chain AND doubles
// the grid (2 blocks/CU) -> latency overlaps. (R7, measured good.)
__global__ __launch_bounds__(256) void sage1_kernel(
    const float* __restrict__ z1, const float* __restrict__ l1T,
    const float* __restrict__ lb, const float* __restrict__ w1pT,
    float* __restrict__ z2) {
    const int bx = blockIdx.x;
    const int bb = bx >> 4, chunk = (bx >> 1) & 7, ohalf = bx & 1;
    __shared__ float h[32 * 256];
    __shared__ float sl[256];
    __shared__ float part[2][128];
    __shared__ float pacc[2][4][128];
    const int t = threadIdx.x;
    const int oo = t & 127, dh = t >> 7;
    const int o = ohalf * 128 + oo;
    const float* zb = z1 + bb * 8192;
    for (int idx = t; idx < 8192; idx += 256) h[idx] = zb[idx];
    __syncthreads();
    {
        float s = 0.f;
#pragma unroll
        for (int n = 0; n < 32; ++n) s += h[n * 256 + t];
        sl[t] = s * (1.f / 31.f);
    }
    __syncthreads();
    const int d0b = dh * 128;
    float c = 0.f;
#pragma unroll 4
    for (int d = 0; d < 128; ++d) c = fmaf(sl[d0b + d], l1T[(d0b + d) * 256 + o], c);
    part[dh][oo] = c;
    float acc[4] = {0.f, 0.f, 0.f, 0.f};
    for (int d = 0; d < 128; d += 4) {
        float wv0 = w1pT[(d0b + d + 0) * 256 + o];
        float wv1 = w1pT[(d0b + d + 1) * 256 + o];
        float wv2 = w1pT[(d0b + d + 2) * 256 + o];
        float wv3 = w1pT[(d0b + d + 3) * 256 + o];
#pragma unroll
        for (int i = 0; i < 4; ++i) {
            f32x4 hv = *(const f32x4*)&h[(chunk * 4 + i) * 256 + d0b + d];
            acc[i] = fmaf(hv[0], wv0, acc[i]);
            acc[i] = fmaf(hv[1], wv1, acc[i]);
            acc[i] = fmaf(hv[2], wv2, acc[i]);
            acc[i] = fmaf(hv[3], wv3, acc[i]);
        }
    }
#pragma unroll
    for (int i = 0; i < 4; ++i) pacc[dh][i][oo] = acc[i];
    __syncthreads();
    const float cf = part[0][oo] + part[1][oo] + lb[o];
#pragma unroll
    for (int ii = 0; ii < 2; ++ii) {
        const int i = dh * 2 + ii;
        float v = cf + pacc[0][i][oo] + pacc[1][i][oo];
        z2[(bb * 32 + chunk * 4 + i) * 256 + o] = fmaxf(v, 0.f);
    }
}

// sage2: grid 512 = (bb 32, chunk 16). Block = 2 nodes x 128 outputs x 2
// d-halves (256 thr). Same d-split rationale as sage1.
__global__ __launch_bounds__(256) void sage2_kernel(
    const float* __restrict__ z2, const float* __restrict__ l2T,
    const float* __restrict__ lb, const float* __restrict__ w2pT,
    float* __restrict__ out) {
    const int bx = blockIdx.x;
    const int bb = bx >> 4, chunk = bx & 15;
    __shared__ float h[32 * 256];
    __shared__ float sl[256];
    __shared__ float part[2][128];
    __shared__ float pacc[2][2][128];
    const int t = threadIdx.x;
    const int oo = t & 127, dh = t >> 7;
    const float* zb = z2 + bb * 8192;
    for (int idx = t; idx < 8192; idx += 256) h[idx] = zb[idx];
    __syncthreads();
    {
        float s = 0.f;
#pragma unroll
        for (int n = 0; n < 32; ++n) s += h[n * 256 + t];
        sl[t] = s * (1.f / 31.f);
    }
    __syncthreads();
    const int d0b = dh * 128;
    const int n0 = chunk * 2;
    float c = 0.f;
#pragma unroll 4
    for (int d = 0; d < 128; ++d) c = fmaf(sl[d0b + d], l2T[(d0b + d) * 128 + oo], c);
    part[dh][oo] = c;
    float acc[2] = {0.f, 0.f};
    for (int d = 0; d < 128; d += 4) {
        float wv0 = w2pT[(d0b + d + 0) * 128 + oo];
        float wv1 = w2pT[(d0b + d + 1) * 128 + oo];
        float wv2 = w2pT[(d0b + d + 2) * 128 + oo];
        float wv3 = w2pT[(d0b + d + 3) * 128 + oo];
#pragma unroll
        for (int i = 0; i < 2; ++i) {
            f32x4 hv = *(const f32x4*)&h[(n0 + i) * 256 + d0b + d];
            acc[i] = fmaf(hv[0], wv0, acc[i]);
            acc[i] = fmaf(hv[1], wv1, acc[i]);
            acc[i] = fmaf(hv[2], wv2, acc[i]);
            acc[i] = fmaf(hv[3], wv3, acc[i]);
        }
    }
#pragma unroll
    for (int i = 0; i < 2; ++i) pacc[dh][i][oo] = acc[i];
    __syncthreads();
    const float cf = part[0][oo] + part[1][oo] + lb[oo];
    {
        const int i = dh;    // 256 threads = 2 nodes x 128 outputs
        float v = cf + pacc[0][i][oo] + pacc[1][i][oo];
        out[(size_t)(bb * 32 + n0 + i) * 128 + oo] = v;
    }
}

extern "C" void kernel_launch(void* const* d_in, const int* in_sizes, int n_in,
                              void* d_out, int out_size, void* d_ws, size_t ws_size,
                              hipStream_t stream) {
    const float* x    = (const float*)d_in[0];
    const float* mask = (const float*)d_in[1];
    const float* c1w  = (const float*)d_in[2];
    const float* c1b  = (const float*)d_in[3];
    const float* c2w  = (const float*)d_in[4];
    const float* c2b  = (const float*)d_in[5];
    const float* fcw  = (const float*)d_in[6];
    const float* fcb  = (const float*)d_in[7];
    const float* s1lw = (const float*)d_in[8];
    const float* s1lb = (const float*)d_in[9];
    const float* s1rw = (const float*)d_in[10];
    const float* s2lw = (const float*)d_in[11];
    const float* s2lb = (const float*)d_in[12];
    const float* s2rw = (const float*)d_in[13];
    float* out = (float*)d_out;

    char* ws = (char*)d_ws;
    float* pooled4 = (float*)(ws);
    float* z1      = (float*)(ws + 2048u * 1024);
    float* z2      = (float*)(ws + 3072u * 1024);
    float* l1T     = (float*)(ws + 4096u * 1024);
    float* w1pT    = (float*)(ws + 4352u * 1024);
    float* l2T     = (float*)(ws + 4608u * 1024);
    float* w2pT    = (float*)(ws + 4736u * 1024);
    float* fwT     = (float*)(ws + 4864u * 1024);
    short* w2c     = (short*)(ws + 4992u * 1024);
    short* w1b     = (short*)(ws + 5136u * 1024);

    prep_kernel<<<dim3(288), 256, 0, stream>>>(s1lw, s1rw, s2lw, s2rw, c2w, c1w, c1b,
                                               fcw, l1T, w1pT, l2T, w2pT, fwT, w2c, w1b);
    fused_conv_kernel<<<dim3(4, 1024), 256, 0, stream>>>(x, w1b, w2c, c2b, pooled4);
    fc_kernel<<<dim3(256), 256, 0, stream>>>(pooled4, fwT, fcb, mask, z1);
    sage1_kernel<<<dim3(512), 256, 0, stream>>>(z1, l1T, s1lb, w1pT, z2);
    sage2_kernel<<<dim3(512), 256, 0, stream>>>(z2, l2T, s2lb, w2pT, out);
}